// Round 5
// baseline (116.684 us; speedup 1.0000x reference)
//
#include <hip/hip_runtime.h>

#define G 8192
#define IMG_W 512
#define IMG_H 512
#define TILE 16
#define NTX (IMG_W / TILE)
#define NTY (IMG_H / TILE)
#define BLK 256
#define CAP 1024            // per-tile list capacity (avg ~190)
#define ALPHA_THRESH (1.0f/255.0f)
#define ALPHA_CAP 0.99f
#define TRANS_THRESH 1e-4f

// ws layout (ws = 256 MiB):
//   [0,        32 KB)   ranges   (u32 per gaussian)
//   [32 KB,    36 KB)   counts   (i32 per tile, padded-to-4 list length)
//   [1 MB,    33 MB)    ab       (float4 x 2 per (tile,slot): {mx,my,a,b},{c,op,r,g})
//   [33 MB,   37 MB)    blue     (float per (tile,slot))
#define WS_RANGES 0
#define WS_COUNTS (32 * 1024)
#define WS_AB     (1 << 20)
#define WS_BLUE   (WS_AB + (32 << 20))

// -----------------------------------------------------------------------
// Kernel 0: per-gaussian tile-span packed into one u32. Exact cull:
// alpha >= 1/255 requires sigma <= ln(255*op); ellipse AABB half-extents
// sqrt(2*smax*(A^-1)_ii), inflated so rounding can't cause false exclusion.
// -----------------------------------------------------------------------
__global__ __launch_bounds__(BLK)
void range_kernel(const float* __restrict__ means2d,
                  const float* __restrict__ conics,
                  const float* __restrict__ opac,
                  unsigned int* __restrict__ ranges)
{
    int g = blockIdx.x * BLK + threadIdx.x;
    if (g >= G) return;
    float op = opac[g];
    unsigned int packed = 0xFFu;          // culled
    if (op * 255.0f >= 1.0f) {
        float smax = __logf(op * 255.0f);
        float a = conics[3*g], b = conics[3*g+1], c = conics[3*g+2];
        float det = fmaxf(a * c - b * b, 1e-12f);
        float rx = sqrtf(fmaxf(2.0f * smax * c / det, 0.0f)) * 1.0001f + 0.01f;
        float ry = sqrtf(fmaxf(2.0f * smax * a / det, 0.0f)) * 1.0001f + 0.01f;
        float mx = means2d[2*g], my = means2d[2*g+1];
        int txmin = (int)ceilf ((mx - rx - 15.5f) * 0.0625f);
        int txmax = (int)floorf((mx + rx -  0.5f) * 0.0625f);
        int tymin = (int)ceilf ((my - ry - 15.5f) * 0.0625f);
        int tymax = (int)floorf((my + ry -  0.5f) * 0.0625f);
        if (!(txmax < 0 || txmin > NTX-1 || tymax < 0 || tymin > NTY-1 ||
              txmin > txmax || tymin > tymax)) {
            txmin = max(txmin, 0); txmax = min(txmax, NTX-1);
            tymin = max(tymin, 0); tymax = min(tymax, NTY-1);
            packed = (unsigned)txmin | ((unsigned)txmax << 8)
                   | ((unsigned)tymin << 16) | ((unsigned)tymax << 24);
        }
    }
    ranges[g] = packed;
}

__device__ __forceinline__ int hitp(unsigned p, unsigned btx, unsigned bty)
{
    return (btx >= (p & 0xffu)) & (btx <= ((p >> 8) & 0xffu)) &
           (bty >= ((p >> 16) & 0xffu)) & (bty <= (p >> 24));
}

// -----------------------------------------------------------------------
// Kernel 1 (one block per tile): validated Phase-1 ballot compaction +
// Phase-2 rank sort (stable argsort by (depth,idx) restricted to tile),
// then MATERIALIZE sorted packed records to global ws, zero-padded to a
// multiple of 4 (zero records are exact no-ops: al = 0*exp(0) = 0).
// -----------------------------------------------------------------------
__global__ __launch_bounds__(BLK)
void bin_kernel(const unsigned int* __restrict__ ranges,
                const float* __restrict__ depths,
                const float* __restrict__ means2d,
                const float* __restrict__ conics,
                const float* __restrict__ colors,
                const float* __restrict__ opac,
                float4* __restrict__ ab,
                float*  __restrict__ blue,
                int*    __restrict__ counts)
{
    __shared__ unsigned short slist[CAP];
    __shared__ unsigned long long keys[CAP];
    __shared__ int woff[4];

    const int t = threadIdx.x;
    const int lane = t & 63, w = t >> 6;
    const unsigned btx = blockIdx.x, bty = blockIdx.y;
    const int tile = bty * NTX + btx;

    // ---- Phase 1, pass A: load + count ----
    const uint4* r4 = (const uint4*)ranges;
    const int wbase = w * (G / 4);
    uint4 rv[8];
    #pragma unroll
    for (int i = 0; i < 8; ++i)
        rv[i] = r4[(wbase >> 2) + i * 64 + lane];

    int cnt = 0;
    #pragma unroll
    for (int i = 0; i < 8; ++i)
        cnt += hitp(rv[i].x, btx, bty) + hitp(rv[i].y, btx, bty)
             + hitp(rv[i].z, btx, bty) + hitp(rv[i].w, btx, bty);
    #pragma unroll
    for (int d = 1; d < 64; d <<= 1) cnt += __shfl_xor(cnt, d);
    if (lane == 0) woff[w] = cnt;
    __syncthreads();

    int offs = 0;
    for (int ww = 0; ww < w; ++ww) offs += woff[ww];
    const int N = min(woff[0] + woff[1] + woff[2] + woff[3], CAP);

    // ---- Phase 1, pass B: ballot compaction (index-ordered) ----
    const unsigned long long lt = (1ull << lane) - 1ull;
    #pragma unroll
    for (int i = 0; i < 8; ++i) {
        int gbase = wbase + i * 256 + lane * 4;
        int h0 = hitp(rv[i].x, btx, bty), h1 = hitp(rv[i].y, btx, bty);
        int h2 = hitp(rv[i].z, btx, bty), h3 = hitp(rv[i].w, btx, bty);
        unsigned long long m0 = __ballot(h0), m1 = __ballot(h1);
        unsigned long long m2 = __ballot(h2), m3 = __ballot(h3);
        int pos = offs + __popcll(m0 & lt) + __popcll(m1 & lt)
                       + __popcll(m2 & lt) + __popcll(m3 & lt);
        if (h0) { if (pos < CAP) slist[pos] = (unsigned short)(gbase    ); pos++; }
        if (h1) { if (pos < CAP) slist[pos] = (unsigned short)(gbase + 1); pos++; }
        if (h2) { if (pos < CAP) slist[pos] = (unsigned short)(gbase + 2); pos++; }
        if (h3) { if (pos < CAP) slist[pos] = (unsigned short)(gbase + 3); pos++; }
        offs += __popcll(m0) + __popcll(m1) + __popcll(m2) + __popcll(m3);
    }
    __syncthreads();

    // ---- Phase 2: rank sort (stable argsort by (depth, idx)) ----
    for (int i = t; i < N; i += BLK) {
        unsigned idx = slist[i];
        keys[i] = ((unsigned long long)__float_as_uint(depths[idx]) << 13)
                | (unsigned long long)idx;
    }
    __syncthreads();
    for (int i = t; i < N; i += BLK) {
        unsigned long long ke = keys[i];
        int r = 0;
        #pragma unroll 4
        for (int j = 0; j < N; ++j) r += (keys[j] < ke);
        slist[r] = (unsigned short)(ke & 0x1fffull);
    }
    __syncthreads();

    // ---- Phase 3: materialize sorted packed records ----
    const int N4 = (N + 3) & ~3;
    const long long base = (long long)tile * CAP;
    for (int i = t; i < N4; i += BLK) {
        float4 a0 = make_float4(0.f, 0.f, 0.f, 0.f);
        float4 b0 = make_float4(0.f, 0.f, 0.f, 0.f);
        float  bl = 0.f;
        if (i < N) {
            int idx = slist[i];
            a0 = make_float4(means2d[2*idx], means2d[2*idx+1],
                             conics[3*idx], conics[3*idx+1]);
            b0 = make_float4(conics[3*idx+2], opac[idx],
                             colors[3*idx], colors[3*idx+1]);
            bl = colors[3*idx+2];
        }
        ab[(base + i) * 2]     = a0;
        ab[(base + i) * 2 + 1] = b0;
        blue[base + i] = bl;
    }
    if (t == 0) counts[tile] = N4;
}

// -----------------------------------------------------------------------
// Kernel 2: one WAVE (64 thr) per 16x4 pixel strip; 4 strips per tile.
// No LDS, no barriers. Inner loop reads the tile's sorted records at
// loop-uniform addresses -> scalar/L1-broadcast loads, off the LDS pipe.
// Per-lane divergent break at T<1e-4 group boundaries (error <= 3e-4,
// validated in Round 4). Zero-padded slots are exact no-ops.
// -----------------------------------------------------------------------
__global__ __launch_bounds__(64)
void raster_kernel(const float4* __restrict__ ab,
                   const float*  __restrict__ blue,
                   const int*    __restrict__ counts,
                   float*        __restrict__ out)
{
    const int tx_tile = blockIdx.x >> 2;
    const int z       = blockIdx.x & 3;
    const int ty_tile = blockIdx.y;
    const int tile    = ty_tile * NTX + tx_tile;
    const int lane    = threadIdx.x;

    const int x = tx_tile * TILE + (lane & 15);
    const int y = ty_tile * TILE + z * 4 + (lane >> 4);
    const float px = (float)x + 0.5f;
    const float py = (float)y + 0.5f;

    const int N4 = counts[tile];
    const long long base = (long long)tile * CAP;

    float T = 1.0f, accr = 0.0f, accg = 0.0f, accb = 0.0f;

    for (int i = 0; i < N4; i += 4) {
        #pragma unroll
        for (int u = 0; u < 4; ++u) {
            float4 q0 = ab[(base + i + u) * 2];
            float4 q1 = ab[(base + i + u) * 2 + 1];
            float  bl = blue[base + i + u];
            float dx = px - q0.x;
            float dy = py - q0.y;
            float sigma = 0.5f * (q0.z*dx*dx + q1.x*dy*dy) + q0.w*dx*dy;
            float al = q1.y * __expf(-sigma);
            bool ok = (sigma >= 0.0f) && (al >= ALPHA_THRESH);
            al = ok ? fminf(al, ALPHA_CAP) : 0.0f;
            float wgt = al * T;
            accr = fmaf(wgt, q1.z, accr);
            accg = fmaf(wgt, q1.w, accg);
            accb = fmaf(wgt, bl,   accb);
            T *= (1.0f - al);
        }
        if (T < TRANS_THRESH) break;   // per-lane divergent exit (exec-masked)
    }

    const int o = (y * IMG_W + x) * 3;
    out[o]     = accr;
    out[o + 1] = accg;
    out[o + 2] = accb;   // BG = 0 -> t_rem term vanishes
}

extern "C" void kernel_launch(void* const* d_in, const int* in_sizes, int n_in,
                              void* d_out, int out_size, void* d_ws, size_t ws_size,
                              hipStream_t stream)
{
    const float* means2d = (const float*)d_in[0];  // (G,2)
    const float* conics  = (const float*)d_in[1];  // (G,3)
    const float* colors  = (const float*)d_in[2];  // (G,3)
    const float* opac    = (const float*)d_in[3];  // (G,)
    const float* depths  = (const float*)d_in[4];  // (G,)
    float* out = (float*)d_out;

    char* ws = (char*)d_ws;
    unsigned int* ranges = (unsigned int*)(ws + WS_RANGES);
    int*          counts = (int*)         (ws + WS_COUNTS);
    float4*       ab     = (float4*)      (ws + WS_AB);
    float*        blue   = (float*)       (ws + WS_BLUE);

    range_kernel<<<G / BLK, BLK, 0, stream>>>(means2d, conics, opac, ranges);
    bin_kernel<<<dim3(NTX, NTY), BLK, 0, stream>>>(
        ranges, depths, means2d, conics, colors, opac, ab, blue, counts);
    raster_kernel<<<dim3(NTX * 4, NTY), 64, 0, stream>>>(ab, blue, counts, out);
}

// Round 6
// 106.552 us; speedup vs baseline: 1.0951x; 1.0951x over previous
//
#include <hip/hip_runtime.h>

#define G 8192
#define IMG_W 512
#define IMG_H 512
#define TILE 16
#define NTX (IMG_W / TILE)
#define NTY (IMG_H / TILE)
#define BLK 256
#define CAP 1024            // per-tile list capacity (avg ~190)
#define ALPHA_THRESH (1.0f/255.0f)
#define ALPHA_CAP 0.99f
#define TRANS_THRESH 1e-4f

// -----------------------------------------------------------------------
// Kernel 0: per-gaussian tile-span packed into one u32. Exact cull:
// alpha >= 1/255 requires sigma <= ln(255*op); ellipse AABB half-extents
// sqrt(2*smax*(A^-1)_ii), inflated so rounding can't cause false exclusion.
// -----------------------------------------------------------------------
__global__ __launch_bounds__(BLK)
void range_kernel(const float* __restrict__ means2d,
                  const float* __restrict__ conics,
                  const float* __restrict__ opac,
                  unsigned int* __restrict__ ranges)
{
    int g = blockIdx.x * BLK + threadIdx.x;
    if (g >= G) return;
    float op = opac[g];
    unsigned int packed = 0xFFu;          // culled
    if (op * 255.0f >= 1.0f) {
        float smax = __logf(op * 255.0f);
        float a = conics[3*g], b = conics[3*g+1], c = conics[3*g+2];
        float det = fmaxf(a * c - b * b, 1e-12f);
        float rx = sqrtf(fmaxf(2.0f * smax * c / det, 0.0f)) * 1.0001f + 0.01f;
        float ry = sqrtf(fmaxf(2.0f * smax * a / det, 0.0f)) * 1.0001f + 0.01f;
        float mx = means2d[2*g], my = means2d[2*g+1];
        int txmin = (int)ceilf ((mx - rx - 15.5f) * 0.0625f);
        int txmax = (int)floorf((mx + rx -  0.5f) * 0.0625f);
        int tymin = (int)ceilf ((my - ry - 15.5f) * 0.0625f);
        int tymax = (int)floorf((my + ry -  0.5f) * 0.0625f);
        if (!(txmax < 0 || txmin > NTX-1 || tymax < 0 || tymin > NTY-1 ||
              txmin > txmax || tymin > tymax)) {
            txmin = max(txmin, 0); txmax = min(txmax, NTX-1);
            tymin = max(tymin, 0); tymax = min(tymax, NTY-1);
            packed = (unsigned)txmin | ((unsigned)txmax << 8)
                   | ((unsigned)tymin << 16) | ((unsigned)tymax << 24);
        }
    }
    ranges[g] = packed;
}

__device__ __forceinline__ int hitp(unsigned p, unsigned btx, unsigned bty)
{
    return (btx >= (p & 0xffu)) & (btx <= ((p >> 8) & 0xffu)) &
           (bty >= ((p >> 16) & 0xffu)) & (bty <= (p >> 24));
}

// register-file broadcast: record j lives in lane j's VGPRs
__device__ __forceinline__ float rdl(float v, int l)
{
    return __int_as_float(__builtin_amdgcn_readlane(__float_as_int(v), l));
}

// -----------------------------------------------------------------------
// Fused tile kernel (one block per 16x16 tile, 256 threads = 4 waves):
//  Phase 1: validated barrier-free two-pass scan + ballot compaction
//           (index-ordered) into LDS slist.
//  Phase 2: validated rank sort by (depth_bits<<13)|idx — reproduces the
//           reference's stable argsort restricted to this tile.
//  Phase 3: NO LDS in the hot loop. Each wave owns a 16x4 pixel strip.
//           Per 64-record chunk: lane i gathers record slist[chunk*64+i]
//           from global (L2-resident, double-buffered in registers); then
//           an unrolled loop broadcasts record j from lane j via
//           v_readlane (VALU/scalar path — off the LDS pipe, which was
//           the measured 38 us wall in R4). Wave-uniform early exit when
//           all 64 lanes have T < 1e-4 (extra contribution <= 1e-4).
// -----------------------------------------------------------------------
__global__ __launch_bounds__(BLK)
void tile_kernel(const unsigned int* __restrict__ ranges,
                 const float* __restrict__ depths,
                 const float* __restrict__ means2d,
                 const float* __restrict__ conics,
                 const float* __restrict__ colors,
                 const float* __restrict__ opac,
                 float*       __restrict__ out)
{
    __shared__ unsigned short slist[CAP];
    __shared__ unsigned long long keys[CAP];
    __shared__ int woff[4];

    const int t = threadIdx.x;
    const int lane = t & 63, w = t >> 6;
    const unsigned btx = blockIdx.x, bty = blockIdx.y;

    // ---- Phase 1, pass A: load + count ----
    const uint4* r4 = (const uint4*)ranges;
    const int wbase = w * (G / 4);
    uint4 rv[8];
    #pragma unroll
    for (int i = 0; i < 8; ++i)
        rv[i] = r4[(wbase >> 2) + i * 64 + lane];

    int cnt = 0;
    #pragma unroll
    for (int i = 0; i < 8; ++i)
        cnt += hitp(rv[i].x, btx, bty) + hitp(rv[i].y, btx, bty)
             + hitp(rv[i].z, btx, bty) + hitp(rv[i].w, btx, bty);
    #pragma unroll
    for (int d = 1; d < 64; d <<= 1) cnt += __shfl_xor(cnt, d);
    if (lane == 0) woff[w] = cnt;
    __syncthreads();

    int offs = 0;
    for (int ww = 0; ww < w; ++ww) offs += woff[ww];
    const int N = min(woff[0] + woff[1] + woff[2] + woff[3], CAP);

    // ---- Phase 1, pass B: ballot compaction (index-ordered) ----
    const unsigned long long lt = (1ull << lane) - 1ull;
    #pragma unroll
    for (int i = 0; i < 8; ++i) {
        int gbase = wbase + i * 256 + lane * 4;
        int h0 = hitp(rv[i].x, btx, bty), h1 = hitp(rv[i].y, btx, bty);
        int h2 = hitp(rv[i].z, btx, bty), h3 = hitp(rv[i].w, btx, bty);
        unsigned long long m0 = __ballot(h0), m1 = __ballot(h1);
        unsigned long long m2 = __ballot(h2), m3 = __ballot(h3);
        int pos = offs + __popcll(m0 & lt) + __popcll(m1 & lt)
                       + __popcll(m2 & lt) + __popcll(m3 & lt);
        if (h0) { if (pos < CAP) slist[pos] = (unsigned short)(gbase    ); pos++; }
        if (h1) { if (pos < CAP) slist[pos] = (unsigned short)(gbase + 1); pos++; }
        if (h2) { if (pos < CAP) slist[pos] = (unsigned short)(gbase + 2); pos++; }
        if (h3) { if (pos < CAP) slist[pos] = (unsigned short)(gbase + 3); pos++; }
        offs += __popcll(m0) + __popcll(m1) + __popcll(m2) + __popcll(m3);
    }
    __syncthreads();

    // ---- Phase 2: rank sort (stable argsort by (depth, idx)) ----
    for (int i = t; i < N; i += BLK) {
        unsigned idx = slist[i];
        keys[i] = ((unsigned long long)__float_as_uint(depths[idx]) << 13)
                | (unsigned long long)idx;
    }
    __syncthreads();
    for (int i = t; i < N; i += BLK) {
        unsigned long long ke = keys[i];
        int r = 0;
        #pragma unroll 4
        for (int j = 0; j < N; ++j) r += (keys[j] < ke);
        slist[r] = (unsigned short)(ke & 0x1fffull);
    }
    __syncthreads();

    // ---- Phase 3: registerized broadcast compositing ----
    const float px = (float)(btx * TILE + (lane & 15)) + 0.5f;
    const float py = (float)(bty * TILE + w * 4 + (lane >> 4)) + 0.5f;

    float T = 1.0f, accr = 0.0f, accg = 0.0f, accb = 0.0f;
    const int nchunk = (N + 63) >> 6;

    float cmx, cmy, ca2, cb, cc2, cop, cr, cg, cbl;
    float nmx, nmy, na2, nb, nc2, nop, nr, ng, nbl;

    auto fetch = [&](int c, float& mx, float& my, float& a2, float& b,
                     float& c2, float& op, float& r, float& g, float& bl) {
        int pos = (c << 6) + lane;
        if (pos < N) {
            int idx = slist[pos];
            mx = means2d[2*idx];      my = means2d[2*idx + 1];
            float a = conics[3*idx];  b  = conics[3*idx + 1];
            float cc = conics[3*idx + 2];
            a2 = 0.5f * a;            c2 = 0.5f * cc;
            r  = colors[3*idx];       g  = colors[3*idx + 1];
            bl = colors[3*idx + 2];   op = opac[idx];
        } else {  // padded slot: op=0 -> alpha=0 -> exact no-op
            mx = 0.f; my = 0.f; a2 = 0.f; b = 0.f; c2 = 0.f;
            op = 0.f; r = 0.f; g = 0.f; bl = 0.f;
        }
    };

    if (nchunk > 0)
        fetch(0, cmx, cmy, ca2, cb, cc2, cop, cr, cg, cbl);

    bool alive = true;
    for (int c = 0; c < nchunk && alive; ++c) {
        if (c + 1 < nchunk)   // prefetch next chunk (overlaps broadcast loop)
            fetch(c + 1, nmx, nmy, na2, nb, nc2, nop, nr, ng, nbl);
        for (int j = 0; j < 64; j += 8) {
            #pragma unroll
            for (int u = 0; u < 8; ++u) {
                int l = j + u;
                float mx = rdl(cmx, l), my = rdl(cmy, l);
                float a2 = rdl(ca2, l), b  = rdl(cb, l), c2 = rdl(cc2, l);
                float op = rdl(cop, l), r  = rdl(cr, l), g  = rdl(cg, l);
                float bl = rdl(cbl, l);
                float dx = px - mx;
                float dy = py - my;
                float sigma = fmaf(fmaf(a2, dx, b * dy), dx, c2 * dy * dy);
                float al = op * __expf(-sigma);
                bool ok = (sigma >= 0.0f) && (al >= ALPHA_THRESH);
                al = ok ? fminf(al, ALPHA_CAP) : 0.0f;
                float wgt = al * T;
                accr = fmaf(wgt, r,  accr);
                accg = fmaf(wgt, g,  accg);
                accb = fmaf(wgt, bl, accb);
                T *= (1.0f - al);
            }
            if (!__any(T >= TRANS_THRESH)) { alive = false; break; }
        }
        cmx = nmx; cmy = nmy; ca2 = na2; cb = nb; cc2 = nc2;
        cop = nop; cr = nr; cg = ng; cbl = nbl;
    }

    const int x = btx * TILE + (lane & 15);
    const int y = bty * TILE + w * 4 + (lane >> 4);
    const int o = (y * IMG_W + x) * 3;
    out[o]     = accr;
    out[o + 1] = accg;
    out[o + 2] = accb;   // BG = 0 -> t_rem term vanishes
}

extern "C" void kernel_launch(void* const* d_in, const int* in_sizes, int n_in,
                              void* d_out, int out_size, void* d_ws, size_t ws_size,
                              hipStream_t stream)
{
    const float* means2d = (const float*)d_in[0];  // (G,2)
    const float* conics  = (const float*)d_in[1];  // (G,3)
    const float* colors  = (const float*)d_in[2];  // (G,3)
    const float* opac    = (const float*)d_in[3];  // (G,)
    const float* depths  = (const float*)d_in[4];  // (G,)
    float* out = (float*)d_out;
    unsigned int* ranges = (unsigned int*)d_ws;    // G u32 = 32 KB of ws

    range_kernel<<<G / BLK, BLK, 0, stream>>>(means2d, conics, opac, ranges);
    tile_kernel<<<dim3(NTX, NTY), BLK, 0, stream>>>(
        ranges, depths, means2d, conics, colors, opac, out);
}

// Round 7
// 96.249 us; speedup vs baseline: 1.2123x; 1.1070x over previous
//
#include <hip/hip_runtime.h>
#include <hip/hip_fp16.h>

#define G 8192
#define IMG_W 512
#define IMG_H 512
#define TILE 16
#define NTX (IMG_W / TILE)   // 32
#define NTY (IMG_H / TILE)   // 32
#define BLK 256
#define CAP 1024             // per-tile list capacity (avg ~190)
#define ALPHA_THRESH (1.0f/255.0f)
#define ALPHA_CAP 0.99f
#define TRANS_THRESH 1e-4f

// ws layout:
//   [0,     32 KB)  ranges (u32 per gaussian)
//   [32 KB, 36 KB)  counts (i32 per tile: list length padded to 64)
//   [1 MB,  33 MB)  rec    (2 x float4 per (tile,slot):
//                           {mx,my,a/2,b}, {c/2,op, rg(half2), blue})
#define WS_RANGES 0
#define WS_COUNTS (32 * 1024)
#define WS_REC    (1 << 20)

// -----------------------------------------------------------------------
// Kernel 0: per-gaussian tile-span packed into one u32. Exact cull:
// alpha >= 1/255 requires sigma <= ln(255*op); ellipse AABB half-extents
// sqrt(2*smax*(A^-1)_ii), inflated so rounding can't cause false exclusion.
// -----------------------------------------------------------------------
__global__ __launch_bounds__(BLK)
void range_kernel(const float* __restrict__ means2d,
                  const float* __restrict__ conics,
                  const float* __restrict__ opac,
                  unsigned int* __restrict__ ranges)
{
    int g = blockIdx.x * BLK + threadIdx.x;
    if (g >= G) return;
    float op = opac[g];
    unsigned int packed = 0xFFu;          // culled
    if (op * 255.0f >= 1.0f) {
        float smax = __logf(op * 255.0f);
        float a = conics[3*g], b = conics[3*g+1], c = conics[3*g+2];
        float det = fmaxf(a * c - b * b, 1e-12f);
        float rx = sqrtf(fmaxf(2.0f * smax * c / det, 0.0f)) * 1.0001f + 0.01f;
        float ry = sqrtf(fmaxf(2.0f * smax * a / det, 0.0f)) * 1.0001f + 0.01f;
        float mx = means2d[2*g], my = means2d[2*g+1];
        int txmin = (int)ceilf ((mx - rx - 15.5f) * 0.0625f);
        int txmax = (int)floorf((mx + rx -  0.5f) * 0.0625f);
        int tymin = (int)ceilf ((my - ry - 15.5f) * 0.0625f);
        int tymax = (int)floorf((my + ry -  0.5f) * 0.0625f);
        if (!(txmax < 0 || txmin > NTX-1 || tymax < 0 || tymin > NTY-1 ||
              txmin > txmax || tymin > tymax)) {
            txmin = max(txmin, 0); txmax = min(txmax, NTX-1);
            tymin = max(tymin, 0); tymax = min(tymax, NTY-1);
            packed = (unsigned)txmin | ((unsigned)txmax << 8)
                   | ((unsigned)tymin << 16) | ((unsigned)tymax << 24);
        }
    }
    ranges[g] = packed;
}

__device__ __forceinline__ int hitp(unsigned p, unsigned btx, unsigned bty)
{
    return (btx >= (p & 0xffu)) & (btx <= ((p >> 8) & 0xffu)) &
           (bty >= ((p >> 16) & 0xffu)) & (bty <= (p >> 24));
}

// -----------------------------------------------------------------------
// Kernel 1 (one block per tile): validated Phase-1 ballot compaction +
// Phase-2 rank sort (stable argsort by (depth,idx) restricted to tile),
// then materialize sorted packed records to ws, zero-padded to a multiple
// of 64 (zero records: sigma=0>=0, alpha=0*exp(0)=0 -> exact no-ops).
// Record = {mx,my,a/2,b} fp32 + {c/2, op, (r,g) half2, blue} — 32 B.
// fp16 color quantization error <= 2^-11 (weights sum <= 1) ~ 5e-4.
// -----------------------------------------------------------------------
__global__ __launch_bounds__(BLK)
void bin_kernel(const unsigned int* __restrict__ ranges,
                const float* __restrict__ depths,
                const float* __restrict__ means2d,
                const float* __restrict__ conics,
                const float* __restrict__ colors,
                const float* __restrict__ opac,
                float4* __restrict__ rec,
                int*    __restrict__ counts)
{
    __shared__ unsigned short slist[CAP];
    __shared__ unsigned long long keys[CAP];
    __shared__ int woff[4];

    const int t = threadIdx.x;
    const int lane = t & 63, w = t >> 6;
    const unsigned btx = blockIdx.x, bty = blockIdx.y;
    const int tile = bty * NTX + btx;

    // ---- Phase 1, pass A: load + count ----
    const uint4* r4 = (const uint4*)ranges;
    const int wbase = w * (G / 4);
    uint4 rv[8];
    #pragma unroll
    for (int i = 0; i < 8; ++i)
        rv[i] = r4[(wbase >> 2) + i * 64 + lane];

    int cnt = 0;
    #pragma unroll
    for (int i = 0; i < 8; ++i)
        cnt += hitp(rv[i].x, btx, bty) + hitp(rv[i].y, btx, bty)
             + hitp(rv[i].z, btx, bty) + hitp(rv[i].w, btx, bty);
    #pragma unroll
    for (int d = 1; d < 64; d <<= 1) cnt += __shfl_xor(cnt, d);
    if (lane == 0) woff[w] = cnt;
    __syncthreads();

    int offs = 0;
    for (int ww = 0; ww < w; ++ww) offs += woff[ww];
    const int N = min(woff[0] + woff[1] + woff[2] + woff[3], CAP - 63);

    // ---- Phase 1, pass B: ballot compaction (index-ordered) ----
    const unsigned long long lt = (1ull << lane) - 1ull;
    #pragma unroll
    for (int i = 0; i < 8; ++i) {
        int gbase = wbase + i * 256 + lane * 4;
        int h0 = hitp(rv[i].x, btx, bty), h1 = hitp(rv[i].y, btx, bty);
        int h2 = hitp(rv[i].z, btx, bty), h3 = hitp(rv[i].w, btx, bty);
        unsigned long long m0 = __ballot(h0), m1 = __ballot(h1);
        unsigned long long m2 = __ballot(h2), m3 = __ballot(h3);
        int pos = offs + __popcll(m0 & lt) + __popcll(m1 & lt)
                       + __popcll(m2 & lt) + __popcll(m3 & lt);
        if (h0) { if (pos < CAP) slist[pos] = (unsigned short)(gbase    ); pos++; }
        if (h1) { if (pos < CAP) slist[pos] = (unsigned short)(gbase + 1); pos++; }
        if (h2) { if (pos < CAP) slist[pos] = (unsigned short)(gbase + 2); pos++; }
        if (h3) { if (pos < CAP) slist[pos] = (unsigned short)(gbase + 3); pos++; }
        offs += __popcll(m0) + __popcll(m1) + __popcll(m2) + __popcll(m3);
    }
    __syncthreads();

    // ---- Phase 2: rank sort (stable argsort by (depth, idx)) ----
    for (int i = t; i < N; i += BLK) {
        unsigned idx = slist[i];
        keys[i] = ((unsigned long long)__float_as_uint(depths[idx]) << 13)
                | (unsigned long long)idx;
    }
    __syncthreads();
    for (int i = t; i < N; i += BLK) {
        unsigned long long ke = keys[i];
        int r = 0;
        #pragma unroll 4
        for (int j = 0; j < N; ++j) r += (keys[j] < ke);
        slist[r] = (unsigned short)(ke & 0x1fffull);
    }
    __syncthreads();

    // ---- Phase 3: materialize sorted packed records ----
    const int N64 = (N + 63) & ~63;
    const size_t rbase = (size_t)tile * (CAP * 2);
    for (int i = t; i < N64; i += BLK) {
        float4 q0 = make_float4(0.f, 0.f, 0.f, 0.f);
        float4 q1 = make_float4(0.f, 0.f, 0.f, 0.f);
        if (i < N) {
            int idx = slist[i];
            union { float f; __half2 h; } uc;
            uc.h = __floats2half2_rn(colors[3*idx], colors[3*idx + 1]);
            q0 = make_float4(means2d[2*idx], means2d[2*idx + 1],
                             0.5f * conics[3*idx], conics[3*idx + 1]);
            q1 = make_float4(0.5f * conics[3*idx + 2], opac[idx],
                             uc.f, colors[3*idx + 2]);
        }
        rec[rbase + i * 2]     = q0;
        rec[rbase + i * 2 + 1] = q1;
    }
    if (t == 0) counts[tile] = N64;
}

// -----------------------------------------------------------------------
// Kernel 2: one WAVE per 16x8 half-tile (2048 blocks x 64 thr), 2 pixels
// per lane sharing the same x (dx, a*dx^2, b*dx computed once per record
// for both). Records double-buffered through 4 KB LDS: global prefetch
// (registers) overlaps the broadcast loop; single wave -> NO barriers.
// Per record per tile: 2 waves x 2 ds_read_b128 = 48 LDS cyc serving 256
// evals (R4: 120). Wave-uniform early exit every 8 records (err <= 1e-4).
// -----------------------------------------------------------------------
__global__ __launch_bounds__(64)
void raster_kernel(const float4* __restrict__ rec,
                   const int*    __restrict__ counts,
                   float*        __restrict__ out)
{
    __shared__ float4 buf[2][128];   // [buffer][slot*2 + {0,1}]

    const int bx   = blockIdx.x;
    const int tile = bx >> 1;
    const int half = bx & 1;
    const int btx  = tile & (NTX - 1);
    const int bty  = tile >> 5;
    const int lane = threadIdx.x;

    const int x  = btx * TILE + (lane & 15);
    const int y0 = bty * TILE + half * 8 + (lane >> 4);
    const float px  = (float)x  + 0.5f;
    const float py0 = (float)y0 + 0.5f;
    const float py1 = py0 + 4.0f;

    const int N64 = counts[tile];
    const float4* base = rec + (size_t)tile * (CAP * 2);

    float T0 = 1.f, T1 = 1.f;
    float r0a = 0.f, g0a = 0.f, b0a = 0.f;
    float r1a = 0.f, g1a = 0.f, b1a = 0.f;

    if (N64 > 0) {
        const int nch = N64 >> 6;
        float4 p0 = base[lane * 2], p1 = base[lane * 2 + 1];
        int cur = 0;
        buf[0][lane * 2] = p0; buf[0][lane * 2 + 1] = p1;
        bool alive = true;

        for (int c = 0; c < nch && alive; ++c) {
            if (c + 1 < nch) {                      // prefetch next chunk
                const float4* nb = base + (size_t)((c + 1) << 6) * 2;
                p0 = nb[lane * 2]; p1 = nb[lane * 2 + 1];
            }
            const float4* bc = &buf[cur][0];
            for (int j = 0; j < 64; j += 8) {
                #pragma unroll
                for (int u = 0; u < 8; ++u) {
                    float4 q0 = bc[(j + u) * 2];        // ds_read_b128 bcast
                    float4 q1 = bc[(j + u) * 2 + 1];    // ds_read_b128 bcast
                    float dx  = px - q0.x;
                    float bdx = q0.w * dx;
                    float t1  = q0.z * dx * dx;
                    float dy0 = py0 - q0.y;
                    float dy1 = py1 - q0.y;
                    float s0  = fmaf(fmaf(q1.x, dy0, bdx), dy0, t1);
                    float s1  = fmaf(fmaf(q1.x, dy1, bdx), dy1, t1);
                    union { float f; __half2 h; } uc; uc.f = q1.z;
                    float cr = __low2float(uc.h);
                    float cg = __high2float(uc.h);
                    float cb = q1.w;
                    float e0 = q1.y * __expf(-s0);
                    float e1 = q1.y * __expf(-s1);
                    float a0 = (s0 >= 0.f && e0 >= ALPHA_THRESH)
                             ? fminf(e0, ALPHA_CAP) : 0.f;
                    float a1 = (s1 >= 0.f && e1 >= ALPHA_THRESH)
                             ? fminf(e1, ALPHA_CAP) : 0.f;
                    float w0 = a0 * T0, w1 = a1 * T1;
                    r0a = fmaf(w0, cr, r0a); g0a = fmaf(w0, cg, g0a);
                    b0a = fmaf(w0, cb, b0a);
                    r1a = fmaf(w1, cr, r1a); g1a = fmaf(w1, cg, g1a);
                    b1a = fmaf(w1, cb, b1a);
                    T0 *= (1.f - a0); T1 *= (1.f - a1);
                }
                if (!__any(fmaxf(T0, T1) >= TRANS_THRESH)) {
                    alive = false; break;
                }
            }
            if (alive && c + 1 < nch) {
                cur ^= 1;
                buf[cur][lane * 2] = p0; buf[cur][lane * 2 + 1] = p1;
            }
        }
    }

    int o = (y0 * IMG_W + x) * 3;
    out[o] = r0a; out[o + 1] = g0a; out[o + 2] = b0a;   // BG = 0
    o = ((y0 + 4) * IMG_W + x) * 3;
    out[o] = r1a; out[o + 1] = g1a; out[o + 2] = b1a;
}

extern "C" void kernel_launch(void* const* d_in, const int* in_sizes, int n_in,
                              void* d_out, int out_size, void* d_ws, size_t ws_size,
                              hipStream_t stream)
{
    const float* means2d = (const float*)d_in[0];  // (G,2)
    const float* conics  = (const float*)d_in[1];  // (G,3)
    const float* colors  = (const float*)d_in[2];  // (G,3)
    const float* opac    = (const float*)d_in[3];  // (G,)
    const float* depths  = (const float*)d_in[4];  // (G,)
    float* out = (float*)d_out;

    char* ws = (char*)d_ws;
    unsigned int* ranges = (unsigned int*)(ws + WS_RANGES);
    int*          counts = (int*)         (ws + WS_COUNTS);
    float4*       rec    = (float4*)      (ws + WS_REC);

    range_kernel<<<G / BLK, BLK, 0, stream>>>(means2d, conics, opac, ranges);
    bin_kernel<<<dim3(NTX, NTY), BLK, 0, stream>>>(
        ranges, depths, means2d, conics, colors, opac, rec, counts);
    raster_kernel<<<NTX * NTY * 2, 64, 0, stream>>>(rec, counts, out);
}

// Round 8
// 94.295 us; speedup vs baseline: 1.2374x; 1.0207x over previous
//
#include <hip/hip_runtime.h>
#include <hip/hip_fp16.h>

#define G 8192
#define IMG_W 512
#define IMG_H 512
#define TILE 16
#define NTX (IMG_W / TILE)   // 32
#define NTY (IMG_H / TILE)   // 32
#define BLK 256              // range kernel block
#define BLK2 128             // tile kernel: 2 waves per 16x16 tile
#define CAP 1024             // per-tile list capacity (avg ~190)
#define ALPHA_THRESH (1.0f/255.0f)
#define ALPHA_CAP 0.99f
#define TRANS_THRESH 1e-4f

// -----------------------------------------------------------------------
// Kernel 0: per-gaussian tile-span packed into one u32. Exact cull:
// alpha >= 1/255 requires sigma <= ln(255*op); ellipse AABB half-extents
// sqrt(2*smax*(A^-1)_ii), inflated so rounding can't cause false exclusion.
// -----------------------------------------------------------------------
__global__ __launch_bounds__(BLK)
void range_kernel(const float* __restrict__ means2d,
                  const float* __restrict__ conics,
                  const float* __restrict__ opac,
                  unsigned int* __restrict__ ranges)
{
    int g = blockIdx.x * BLK + threadIdx.x;
    if (g >= G) return;
    float op = opac[g];
    unsigned int packed = 0xFFu;          // culled
    if (op * 255.0f >= 1.0f) {
        float smax = __logf(op * 255.0f);
        float a = conics[3*g], b = conics[3*g+1], c = conics[3*g+2];
        float det = fmaxf(a * c - b * b, 1e-12f);
        float rx = sqrtf(fmaxf(2.0f * smax * c / det, 0.0f)) * 1.0001f + 0.01f;
        float ry = sqrtf(fmaxf(2.0f * smax * a / det, 0.0f)) * 1.0001f + 0.01f;
        float mx = means2d[2*g], my = means2d[2*g+1];
        int txmin = (int)ceilf ((mx - rx - 15.5f) * 0.0625f);
        int txmax = (int)floorf((mx + rx -  0.5f) * 0.0625f);
        int tymin = (int)ceilf ((my - ry - 15.5f) * 0.0625f);
        int tymax = (int)floorf((my + ry -  0.5f) * 0.0625f);
        if (!(txmax < 0 || txmin > NTX-1 || tymax < 0 || tymin > NTY-1 ||
              txmin > txmax || tymin > tymax)) {
            txmin = max(txmin, 0); txmax = min(txmax, NTX-1);
            tymin = max(tymin, 0); tymax = min(tymax, NTY-1);
            packed = (unsigned)txmin | ((unsigned)txmax << 8)
                   | ((unsigned)tymin << 16) | ((unsigned)tymax << 24);
        }
    }
    ranges[g] = packed;
}

__device__ __forceinline__ int hitp(unsigned p, unsigned btx, unsigned bty)
{
    return (btx >= (p & 0xffu)) & (btx <= ((p >> 8) & 0xffu)) &
           (bty >= ((p >> 16) & 0xffu)) & (bty <= (p >> 24));
}

// -----------------------------------------------------------------------
// Fused tile kernel: one block (128 thr = 2 waves) per 16x16 tile.
//  Phase 1: two-pass scan; each wave owns a contiguous 4096-gaussian
//           range (re-reads the L1-resident 32 KB table per pass instead
//           of holding 64 VGPRs). Ballot compaction, index-ordered.
//  Phase 2: validated rank sort by (depth_bits<<13)|idx — the stable
//           argsort restricted to this tile.
//  Phase 3: chunks of 128 records staged as 2 x float4 per record
//           ({mx,my,a/2,b}, {c/2,op,rg(half2),blue}); each wave covers
//           16x8 pixels, 2 px/lane sharing x (dx, b*dx, a*dx^2 computed
//           once). Per record per tile: 2 waves x 2 ds_read_b128 = 48
//           LDS cyc (R4: 120). Wave-level early-exit vote every 8
//           records, block vote per chunk (validated, err <= 1e-4).
// -----------------------------------------------------------------------
__global__ __launch_bounds__(BLK2)
void tile_kernel(const unsigned int* __restrict__ ranges,
                 const float* __restrict__ depths,
                 const float* __restrict__ means2d,
                 const float* __restrict__ conics,
                 const float* __restrict__ colors,
                 const float* __restrict__ opac,
                 float*       __restrict__ out)
{
    __shared__ unsigned short slist[CAP];
    __shared__ unsigned long long keys[CAP];
    __shared__ int woff[2];
    __shared__ float4 buf[BLK2 * 2];

    const int t = threadIdx.x;
    const int lane = t & 63, w = t >> 6;
    const unsigned btx = blockIdx.x, bty = blockIdx.y;

    // ---- Phase 1, pass A: count (wave w owns gaussians [w*4096, w*4096+4096)) ----
    const uint4* r4 = (const uint4*)ranges;
    const int wq = w * (4096 / 4);        // uint4 base index

    int cnt = 0;
    #pragma unroll 4
    for (int i = 0; i < 16; ++i) {
        uint4 rv = r4[wq + i * 64 + lane];
        cnt += hitp(rv.x, btx, bty) + hitp(rv.y, btx, bty)
             + hitp(rv.z, btx, bty) + hitp(rv.w, btx, bty);
    }
    #pragma unroll
    for (int d = 1; d < 64; d <<= 1) cnt += __shfl_xor(cnt, d);
    if (lane == 0) woff[w] = cnt;
    __syncthreads();

    int offs = (w == 1) ? woff[0] : 0;
    const int N = min(woff[0] + woff[1], CAP);

    // ---- Phase 1, pass B: ballot compaction (index-ordered; table re-read) ----
    const unsigned long long lt = (1ull << lane) - 1ull;
    #pragma unroll 4
    for (int i = 0; i < 16; ++i) {
        uint4 rv = r4[wq + i * 64 + lane];
        int gbase = w * 4096 + i * 256 + lane * 4;
        int h0 = hitp(rv.x, btx, bty), h1 = hitp(rv.y, btx, bty);
        int h2 = hitp(rv.z, btx, bty), h3 = hitp(rv.w, btx, bty);
        unsigned long long m0 = __ballot(h0), m1 = __ballot(h1);
        unsigned long long m2 = __ballot(h2), m3 = __ballot(h3);
        int pos = offs + __popcll(m0 & lt) + __popcll(m1 & lt)
                       + __popcll(m2 & lt) + __popcll(m3 & lt);
        if (h0) { if (pos < CAP) slist[pos] = (unsigned short)(gbase    ); pos++; }
        if (h1) { if (pos < CAP) slist[pos] = (unsigned short)(gbase + 1); pos++; }
        if (h2) { if (pos < CAP) slist[pos] = (unsigned short)(gbase + 2); pos++; }
        if (h3) { if (pos < CAP) slist[pos] = (unsigned short)(gbase + 3); pos++; }
        offs += __popcll(m0) + __popcll(m1) + __popcll(m2) + __popcll(m3);
    }
    __syncthreads();

    // ---- Phase 2: rank sort (stable argsort by (depth, idx)) ----
    for (int i = t; i < N; i += BLK2) {
        unsigned idx = slist[i];
        keys[i] = ((unsigned long long)__float_as_uint(depths[idx]) << 13)
                | (unsigned long long)idx;
    }
    __syncthreads();
    for (int i = t; i < N; i += BLK2) {
        unsigned long long ke = keys[i];
        int r = 0;
        #pragma unroll 4
        for (int j = 0; j < N; ++j) r += (keys[j] < ke);
        slist[r] = (unsigned short)(ke & 0x1fffull);
    }
    __syncthreads();

    // ---- Phase 3: 2 px/lane compositing (wave w: rows w*4..w*4+3, +8) ----
    const int x  = btx * TILE + (lane & 15);
    const int y0 = bty * TILE + w * 4 + (lane >> 4);
    const float px  = (float)x  + 0.5f;
    const float py0 = (float)y0 + 0.5f;
    const float py1 = py0 + 8.0f;

    float T0 = 1.f, T1 = 1.f;
    float r0a = 0.f, g0a = 0.f, b0a = 0.f;
    float r1a = 0.f, g1a = 0.f, b1a = 0.f;
    bool done = false;

    for (int base = 0; base < N; base += BLK2) {
        const int n = min(BLK2, N - base);
        // stage record base+t (padded slots = zero records -> exact no-ops)
        float4 q0 = make_float4(0.f, 0.f, 0.f, 0.f);
        float4 q1 = make_float4(0.f, 0.f, 0.f, 0.f);
        if (t < n) {
            int idx = slist[base + t];
            union { float f; __half2 h; } uc;
            uc.h = __floats2half2_rn(colors[3*idx], colors[3*idx + 1]);
            q0 = make_float4(means2d[2*idx], means2d[2*idx + 1],
                             0.5f * conics[3*idx], conics[3*idx + 1]);
            q1 = make_float4(0.5f * conics[3*idx + 2], opac[idx],
                             uc.f, colors[3*idx + 2]);
        }
        buf[t * 2] = q0; buf[t * 2 + 1] = q1;
        __syncthreads();

        if (!done) {
            const int n8 = (n + 7) & ~7;
            for (int j = 0; j < n8 && !done; j += 8) {
                #pragma unroll
                for (int u = 0; u < 8; ++u) {
                    float4 c0 = buf[(j + u) * 2];        // ds_read_b128 bcast
                    float4 c1 = buf[(j + u) * 2 + 1];    // ds_read_b128 bcast
                    float dx  = px - c0.x;
                    float bdx = c0.w * dx;
                    float txx = c0.z * dx * dx;
                    float dy0 = py0 - c0.y;
                    float dy1 = py1 - c0.y;
                    float s0  = fmaf(fmaf(c1.x, dy0, bdx), dy0, txx);
                    float s1  = fmaf(fmaf(c1.x, dy1, bdx), dy1, txx);
                    union { float f; __half2 h; } uc; uc.f = c1.z;
                    float cr = __low2float(uc.h);
                    float cg = __high2float(uc.h);
                    float cb = c1.w;
                    float e0 = c1.y * __expf(-s0);
                    float e1 = c1.y * __expf(-s1);
                    float a0 = (s0 >= 0.f && e0 >= ALPHA_THRESH)
                             ? fminf(e0, ALPHA_CAP) : 0.f;
                    float a1 = (s1 >= 0.f && e1 >= ALPHA_THRESH)
                             ? fminf(e1, ALPHA_CAP) : 0.f;
                    float w0 = a0 * T0, w1 = a1 * T1;
                    r0a = fmaf(w0, cr, r0a); g0a = fmaf(w0, cg, g0a);
                    b0a = fmaf(w0, cb, b0a);
                    r1a = fmaf(w1, cr, r1a); g1a = fmaf(w1, cg, g1a);
                    b1a = fmaf(w1, cb, b1a);
                    T0 *= (1.f - a0); T1 *= (1.f - a1);
                }
                if (!__any(fmaxf(T0, T1) >= TRANS_THRESH)) done = true;
            }
        }
        // barrier doubles as all-done vote + protects buf reuse
        if (__syncthreads_and((int)done)) break;
    }

    int o = (y0 * IMG_W + x) * 3;
    out[o] = r0a; out[o + 1] = g0a; out[o + 2] = b0a;   // BG = 0
    o = ((y0 + 8) * IMG_W + x) * 3;
    out[o] = r1a; out[o + 1] = g1a; out[o + 2] = b1a;
}

extern "C" void kernel_launch(void* const* d_in, const int* in_sizes, int n_in,
                              void* d_out, int out_size, void* d_ws, size_t ws_size,
                              hipStream_t stream)
{
    const float* means2d = (const float*)d_in[0];  // (G,2)
    const float* conics  = (const float*)d_in[1];  // (G,3)
    const float* colors  = (const float*)d_in[2];  // (G,3)
    const float* opac    = (const float*)d_in[3];  // (G,)
    const float* depths  = (const float*)d_in[4];  // (G,)
    float* out = (float*)d_out;
    unsigned int* ranges = (unsigned int*)d_ws;    // G u32 = 32 KB of ws

    range_kernel<<<G / BLK, BLK, 0, stream>>>(means2d, conics, opac, ranges);
    tile_kernel<<<dim3(NTX, NTY), BLK2, 0, stream>>>(
        ranges, depths, means2d, conics, colors, opac, out);
}